// Round 12
// baseline (216.003 us; speedup 1.0000x reference)
//
#include <hip/hip_runtime.h>
#include <hip/hip_fp16.h>
#include <math.h>

// GCN 3-layer, no inter-layer nonlinearity -> algebraic collapse:
//   out = sigmoid( A^3 (x @ Wc) + s2*c1 + s1*c2 + b3 )
//   Wc = W1@W2@W3, c1 = b1@W2@W3, c2 = b2@W3, s1 = A*1, s2 = A*s1
// CSR build: zero global atomics (two-level LDS bucket sort).
// CSR entry packed to 4B: u32 = (fp16_bits(nrm) << 17) | src (nrm>0 -> 15b).
// Aggregation: 3 passes at D=32 on fp16 rows; 8 gathers in flight;
// non-temporal loads/stores for the sequential streams (csr, outputs) so
// they don't evict the 6.4MB gather table from the 4MB/XCD L2.
// NOTE: __builtin_nontemporal_* requires clang vector types, not
// HIP_vector_type -> use ext_vector_type aliases for the stores.

#define EPB 4096   // edges per pass-1 block
#define MAXBKT 512 // >= ceil(N/256)

typedef unsigned uint2_v __attribute__((ext_vector_type(2)));
typedef float    float4_v __attribute__((ext_vector_type(4)));

__device__ __forceinline__ float unpack_w(unsigned u) {
    return __half2float(__ushort_as_half((unsigned short)(u >> 17)));
}
__device__ __forceinline__ unsigned pack_sw(int src, float w) {
    unsigned wb = (unsigned)__half_as_ushort(__float2half_rn(w)) & 0x7FFFu;
    return (wb << 17) | (unsigned)src;
}

// ---------- 1a: per-block bucket histogram (LDS atomics only) ----------
__global__ __launch_bounds__(256) void hist1_kernel(const int* __restrict__ ei,
                                                    int* __restrict__ hist1,
                                                    int nbkt, int nblk1, int E) {
    __shared__ int lh[MAXBKT];
    int tid = threadIdx.x;
    for (int b = tid; b < nbkt; b += 256) lh[b] = 0;
    __syncthreads();
    int base = blockIdx.x * EPB;
    #pragma unroll
    for (int j = 0; j < EPB / 256; ++j) {
        int e = base + j * 256 + tid;
        if (e < E) atomicAdd(&lh[ei[E + e] >> 8], 1);
    }
    __syncthreads();
    for (int b = tid; b < nbkt; b += 256)
        hist1[(size_t)b * nblk1 + blockIdx.x] = lh[b];
}

// ---------- hierarchical exclusive scan ----------
__global__ void scan_block_kernel(const int* __restrict__ counts, int* __restrict__ outp,
                                  int* __restrict__ bsums, int n) {
    __shared__ int s[256];
    int tid = threadIdx.x;
    int i = blockIdx.x * 256 + tid;
    int v = (i < n) ? counts[i] : 0;
    s[tid] = v;
    __syncthreads();
    for (int off = 1; off < 256; off <<= 1) {
        int t = (tid >= off) ? s[tid - off] : 0;
        __syncthreads();
        s[tid] += t;
        __syncthreads();
    }
    if (i < n) outp[i] = s[tid] - v;
    if (tid == 255) bsums[blockIdx.x] = s[255];
}

__global__ void scan_bsums_kernel(int* __restrict__ bsums, int nb) {
    __shared__ int s[1024];
    int tid = threadIdx.x;
    int v = (tid < nb) ? bsums[tid] : 0;
    s[tid] = v;
    __syncthreads();
    for (int off = 1; off < 1024; off <<= 1) {
        int t = (tid >= off) ? s[tid - off] : 0;
        __syncthreads();
        s[tid] += t;
        __syncthreads();
    }
    if (tid < nb) bsums[tid] = s[tid] - v;
}

__global__ void scan_add_kernel(int* __restrict__ outp, const int* __restrict__ bsums,
                                int n, int E) {
    int i = blockIdx.x * 256 + threadIdx.x;
    if (i < n) outp[i] += bsums[i >> 8];
    if (i == n) outp[n] = E;   // sentinel
}

// ---------- 1c: scatter edges to bucket-ordered tmp (LDS cursors) ----------
__global__ __launch_bounds__(256) void bucket_scatter_kernel(const int* __restrict__ ei,
                                                             const float* __restrict__ ew,
                                                             const int* __restrict__ scan1,
                                                             int2* __restrict__ tmp,
                                                             int nbkt, int nblk1, int E) {
    __shared__ int cur[MAXBKT];
    int tid = threadIdx.x;
    for (int b = tid; b < nbkt; b += 256)
        cur[b] = scan1[(size_t)b * nblk1 + blockIdx.x];
    __syncthreads();
    int base = blockIdx.x * EPB;
    #pragma unroll
    for (int j = 0; j < EPB / 256; ++j) {
        int e = base + j * 256 + tid;
        if (e < E) {
            int s = ei[e];
            int d = ei[E + e];
            float w = ew[e];
            int pos = atomicAdd(&cur[d >> 8], 1);
            tmp[pos] = make_int2(s | ((d & 255) << 20), __float_as_int(w));
        }
    }
}

// ---------- 2: per-bucket build: rowptr, packed csr, dinv (all LDS-local) ----------
__global__ __launch_bounds__(256) void bucket_build_kernel(const int* __restrict__ scan1,
                                                           const int2* __restrict__ tmp,
                                                           int* __restrict__ rowptr,
                                                           unsigned* __restrict__ csr,
                                                           float* __restrict__ dinv,
                                                           int nblk1, int N, int E) {
    __shared__ int s[256];
    __shared__ int cur[256];
    __shared__ float wsum[256];
    int b = blockIdx.x;
    int tid = threadIdx.x;
    int beg = scan1[(size_t)b * nblk1];
    int end = scan1[(size_t)(b + 1) * nblk1];

    s[tid] = 0;
    wsum[tid] = 0.f;
    __syncthreads();
    for (int i = beg + tid; i < end; i += 256) {
        int2 r = tmp[i];
        int dl = r.x >> 20;
        atomicAdd(&s[dl], 1);
        atomicAdd(&wsum[dl], __int_as_float(r.y));   // fp32 weights -> exact deg
    }
    __syncthreads();
    int myc = s[tid];
    for (int off = 1; off < 256; off <<= 1) {
        int t = (tid >= off) ? s[tid - off] : 0;
        __syncthreads();
        s[tid] += t;
        __syncthreads();
    }
    int excl = s[tid] - myc;
    cur[tid] = excl;
    int node = b * 256 + tid;
    if (node <= N) rowptr[node] = beg + excl;
    if (node < N)  dinv[node] = rsqrtf(1.0f + wsum[tid]);
    __syncthreads();
    for (int i = beg + tid; i < end; i += 256) {
        int2 r = tmp[i];
        int dl = r.x >> 20;
        int pos = beg + atomicAdd(&cur[dl], 1);
        csr[pos] = pack_sw(r.x & 0xFFFFF, __int_as_float(r.y));
    }
}

// ---------- nrm finalize (in place, packed) + s1 = A*1 ----------
__global__ void nrm_s1_kernel(const float* __restrict__ dinv, const int* __restrict__ rowptr,
                              unsigned* __restrict__ csr, float* __restrict__ s1, int n) {
    int v = blockIdx.x * 256 + threadIdx.x;
    if (v >= n) return;
    float dv = dinv[v];
    float acc = dv * dv;
    int beg = rowptr[v], end = rowptr[v + 1];
    for (int i = beg; i < end; ++i) {
        unsigned u = __builtin_nontemporal_load(&csr[i]);
        int src = u & 0x1FFFF;
        float nm = dv * unpack_w(u) * dinv[src];
        acc += nm;
        __builtin_nontemporal_store(pack_sw(src, nm), &csr[i]);
    }
    s1[v] = acc;
}

// ---------- compose1: U = [W1;b1] @ W2  (65 rows, K=128) ----------
__global__ __launch_bounds__(256) void compose1_kernel(const float* __restrict__ W1,
                                                       const float* __restrict__ b1,
                                                       const float* __restrict__ W2,
                                                       float* __restrict__ U) {
    __shared__ float s[256];
    int r = blockIdx.x;
    int tid = threadIdx.x;
    int c = tid & 63;
    int q = tid >> 6;
    const float* arow = (r < 64) ? &W1[r * 128] : b1;
    float acc = 0.f;
    #pragma unroll 8
    for (int k = q * 32; k < q * 32 + 32; ++k)
        acc += arow[k] * W2[k * 64 + c];
    s[tid] = acc;
    __syncthreads();
    if (q == 0)
        U[r * 64 + c] = s[c] + s[c + 64] + s[c + 128] + s[c + 192];
}

// ---------- compose2: U@W3 -> Wc,c1 ; b2@W3 -> c2 (K=64) ----------
__global__ __launch_bounds__(256) void compose2_kernel(const float* __restrict__ U,
                                                       const float* __restrict__ b2,
                                                       const float* __restrict__ W3,
                                                       float* __restrict__ Wc,
                                                       float* __restrict__ c1,
                                                       float* __restrict__ c2) {
    __shared__ float s[256];
    int r = blockIdx.x;
    int tid = threadIdx.x;
    int c = tid & 31;
    int o = tid >> 5;
    const float* arow = (r < 65) ? &U[r * 64] : b2;
    float acc = 0.f;
    #pragma unroll
    for (int k = o * 8; k < o * 8 + 8; ++k)
        acc += arow[k] * W3[k * 32 + c];
    s[tid] = acc;
    __syncthreads();
    if (o == 0) {
        float v = 0.f;
        #pragma unroll
        for (int j = 0; j < 8; ++j) v += s[c + j * 32];
        if (r < 64) Wc[r * 32 + c] = v;
        else if (r == 64) c1[c] = v;
        else c2[c] = v;
    }
}

// ---------- GEMM: T[n, 32] = X[n, 64] @ Wc[64, 32], output fp16 ----------
template <int K, int D>
__global__ __launch_bounds__(256) void gemm_kernel(const float* __restrict__ X,
                                                   const float* __restrict__ W,
                                                   __half* __restrict__ T, int n) {
    constexpr int NB = 64;
    __shared__ float sW[K * D];
    __shared__ float sX[NB * K];
    int tid = threadIdx.x;
    int base = blockIdx.x * NB;
    int nthis = n - base;
    if (nthis > NB) nthis = NB;

    for (int i = tid * 4; i < K * D; i += 256 * 4)
        *(float4*)&sW[i] = *(const float4*)&W[i];
    for (int i = tid * 4; i < nthis * K; i += 256 * 4)
        *(float4*)&sX[i] = *(const float4*)&X[(size_t)base * K + i];
    __syncthreads();

    constexpr int C4 = D / 4;
    constexpr int NG = 256 / C4;
    int c4 = tid % C4;
    int ng = tid / C4;
    for (int nl = ng; nl < nthis; nl += NG) {
        const float* xr = &sX[nl * K];
        float4 acc = {0.f, 0.f, 0.f, 0.f};
        #pragma unroll
        for (int k = 0; k < K; ++k) {
            float a = xr[k];
            float4 wv = *(const float4*)&sW[k * D + c4 * 4];
            acc.x += a * wv.x; acc.y += a * wv.y;
            acc.z += a * wv.z; acc.w += a * wv.w;
        }
        __half2 h0 = __floats2half2_rn(acc.x, acc.y);
        __half2 h1 = __floats2half2_rn(acc.z, acc.w);
        uint2_v u = { *(unsigned*)&h0, *(unsigned*)&h1 };
        __builtin_nontemporal_store(u, (uint2_v*)&T[(size_t)(base + nl) * D + c4 * 4]);
    }
}

// ---------- agg32: fp16 rows, packed 4B csr, 8 gathers in flight, nt streams ----------
template <int PHASE>
__global__ __launch_bounds__(256) void agg32_kernel(const __half* __restrict__ T,
                                                    const float* __restrict__ dinv,
                                                    const int* __restrict__ rowptr,
                                                    const unsigned* __restrict__ csr,
                                                    const float* __restrict__ s1,
                                                    float* __restrict__ s2,
                                                    const float* __restrict__ c1,
                                                    const float* __restrict__ c2,
                                                    const float* __restrict__ b3,
                                                    void* __restrict__ outp, int n) {
    int c4 = threadIdx.x & 7;                       // 8 lanes x 4 halves = 32 cols
    int node = blockIdx.x * 32 + (threadIdx.x >> 3);
    if (node >= n) return;

    float di = dinv[node];
    float ns = di * di;
    uint2 tu = *(const uint2*)&T[(size_t)node * 32 + c4 * 4];
    float2 t0 = __half22float2(*(__half2*)&tu.x);
    float2 t1 = __half22float2(*(__half2*)&tu.y);
    float4 acc = { t0.x * ns, t0.y * ns, t1.x * ns, t1.y * ns };
    float sacc = (PHASE == 0) ? ns * s1[node] : 0.f;

    int beg = rowptr[node];
    int end = rowptr[node + 1];
    int i = beg;
    // 8-wide: 8 independent csr loads, then 8 independent row-gathers in flight
    for (; i + 8 <= end; i += 8) {
        unsigned u[8];
        #pragma unroll
        for (int k = 0; k < 8; ++k) u[k] = __builtin_nontemporal_load(&csr[i + k]);
        uint2 g[8];
        #pragma unroll
        for (int k = 0; k < 8; ++k)
            g[k] = *(const uint2*)&T[(size_t)(u[k] & 0x1FFFF) * 32 + c4 * 4];
        float sv[8];
        if (PHASE == 0) {
            #pragma unroll
            for (int k = 0; k < 8; ++k) sv[k] = s1[u[k] & 0x1FFFF];
        }
        #pragma unroll
        for (int k = 0; k < 8; ++k) {
            float w = unpack_w(u[k]);
            float2 a0 = __half22float2(*(__half2*)&g[k].x);
            float2 a1 = __half22float2(*(__half2*)&g[k].y);
            acc.x += w * a0.x; acc.y += w * a0.y;
            acc.z += w * a1.x; acc.w += w * a1.y;
            if (PHASE == 0) sacc += w * sv[k];
        }
    }
    // 4-wide
    for (; i + 4 <= end; i += 4) {
        unsigned u[4];
        #pragma unroll
        for (int k = 0; k < 4; ++k) u[k] = __builtin_nontemporal_load(&csr[i + k]);
        uint2 g[4];
        #pragma unroll
        for (int k = 0; k < 4; ++k)
            g[k] = *(const uint2*)&T[(size_t)(u[k] & 0x1FFFF) * 32 + c4 * 4];
        #pragma unroll
        for (int k = 0; k < 4; ++k) {
            float w = unpack_w(u[k]);
            float2 a0 = __half22float2(*(__half2*)&g[k].x);
            float2 a1 = __half22float2(*(__half2*)&g[k].y);
            acc.x += w * a0.x; acc.y += w * a0.y;
            acc.z += w * a1.x; acc.w += w * a1.y;
            if (PHASE == 0) sacc += w * s1[u[k] & 0x1FFFF];
        }
    }
    // scalar tail
    for (; i < end; ++i) {
        unsigned u0 = __builtin_nontemporal_load(&csr[i]);
        int s0 = u0 & 0x1FFFF;
        uint2 g0 = *(const uint2*)&T[(size_t)s0 * 32 + c4 * 4];
        float w0 = unpack_w(u0);
        float2 a0 = __half22float2(*(__half2*)&g0.x);
        float2 a1 = __half22float2(*(__half2*)&g0.y);
        acc.x += w0 * a0.x;
        acc.y += w0 * a0.y;
        acc.z += w0 * a1.x;
        acc.w += w0 * a1.y;
        if (PHASE == 0) sacc += w0 * s1[s0];
    }

    if (PHASE == 0 && c4 == 0) s2[node] = sacc;

    if (PHASE == 2) {
        float a = s2[node], b = s1[node];
        float4 c1v = *(const float4*)&c1[c4 * 4];
        float4 c2v = *(const float4*)&c2[c4 * 4];
        float4 b3v = *(const float4*)&b3[c4 * 4];
        acc.x += a * c1v.x + b * c2v.x + b3v.x;
        acc.y += a * c1v.y + b * c2v.y + b3v.y;
        acc.z += a * c1v.z + b * c2v.z + b3v.z;
        acc.w += a * c1v.w + b * c2v.w + b3v.w;
        acc.x = 1.f / (1.f + __expf(-acc.x));
        acc.y = 1.f / (1.f + __expf(-acc.y));
        acc.z = 1.f / (1.f + __expf(-acc.z));
        acc.w = 1.f / (1.f + __expf(-acc.w));
        float4_v av = { acc.x, acc.y, acc.z, acc.w };
        __builtin_nontemporal_store(av, (float4_v*)&((float*)outp)[(size_t)node * 32 + c4 * 4]);
    } else {
        __half2 h0 = __floats2half2_rn(acc.x, acc.y);
        __half2 h1 = __floats2half2_rn(acc.z, acc.w);
        uint2_v u = { *(unsigned*)&h0, *(unsigned*)&h1 };
        __builtin_nontemporal_store(u, (uint2_v*)&((__half*)outp)[(size_t)node * 32 + c4 * 4]);
    }
}

extern "C" void kernel_launch(void* const* d_in, const int* in_sizes, int n_in,
                              void* d_out, int out_size, void* d_ws, size_t ws_size,
                              hipStream_t stream) {
    const float* x  = (const float*)d_in[0];
    const int*   ei = (const int*)d_in[1];      // [2, E]: row=ei[0:E], col=ei[E:2E]
    const float* ew = (const float*)d_in[2];
    const float* W1 = (const float*)d_in[3];
    const float* b1 = (const float*)d_in[4];
    const float* W2 = (const float*)d_in[5];
    const float* b2 = (const float*)d_in[6];
    const float* W3 = (const float*)d_in[7];
    const float* b3 = (const float*)d_in[8];
    float* out = (float*)d_out;

    const int N = in_sizes[0] / 64;
    const int E = in_sizes[2];

    const int nbkt  = (N + 255) >> 8;
    const int nblk1 = (E + EPB - 1) / EPB;
    const int nscan = nbkt * nblk1;

    auto a16 = [](size_t v) { return (v + 15) & ~(size_t)15; };
    char* p = (char*)d_ws;
    int*      hist1  = (int*)p;      p += a16((size_t)nscan * 4);
    int*      scan1  = (int*)p;      p += a16((size_t)(nscan + 1) * 4);
    int*      bsums  = (int*)p;      p += a16((size_t)1024 * 4);
    int2*     tmp    = (int2*)p;     p += a16((size_t)E * 8);
    int*      rowptr = (int*)p;      p += a16((size_t)(N + 1) * 4);
    unsigned* csr    = (unsigned*)p; p += a16((size_t)E * 4);   // packed {nrm15|src17}
    float*    dinv   = (float*)p;    p += a16((size_t)N * 4);
    float*    s1     = (float*)p;    p += a16((size_t)N * 4);
    float*    s2     = (float*)p;    p += a16((size_t)N * 4);
    float*    Uc     = (float*)p;    p += a16((size_t)65 * 64 * 4);
    float*    Wc     = (float*)p;    p += a16((size_t)64 * 32 * 4);
    float*    c1     = (float*)p;    p += a16((size_t)32 * 4);
    float*    c2     = (float*)p;    p += a16((size_t)32 * 4);
    __half*   y      = (__half*)p;   p += a16((size_t)N * 32 * 2);
    __half*   z      = (__half*)p;   p += a16((size_t)N * 32 * 2);

    const int nbN = (N + 255) / 256;
    const int scanBlocks = (nscan + 255) / 256;

    // CSR build: LDS bucket sort, zero global atomics
    hist1_kernel<<<nblk1, 256, 0, stream>>>(ei, hist1, nbkt, nblk1, E);
    scan_block_kernel<<<scanBlocks, 256, 0, stream>>>(hist1, scan1, bsums, nscan);
    scan_bsums_kernel<<<1, 1024, 0, stream>>>(bsums, scanBlocks);
    scan_add_kernel<<<(nscan + 1 + 255) / 256, 256, 0, stream>>>(scan1, bsums, nscan, E);
    bucket_scatter_kernel<<<nblk1, 256, 0, stream>>>(ei, ew, scan1, tmp, nbkt, nblk1, E);
    bucket_build_kernel<<<nbkt, 256, 0, stream>>>(scan1, tmp, rowptr, csr, dinv, nblk1, N, E);

    // Normalization from CSR
    nrm_s1_kernel<<<nbN, 256, 0, stream>>>(dinv, rowptr, csr, s1, N);

    // Collapsed weights (row-parallel) + dense transform (fp16 rows out)
    compose1_kernel<<<65, 256, 0, stream>>>(W1, b1, W2, Uc);
    compose2_kernel<<<66, 256, 0, stream>>>(Uc, b2, W3, Wc, c1, c2);
    gemm_kernel<64, 32><<<(N + 63) / 64, 256, 0, stream>>>(x, Wc, y, N);

    // Three sparse passes at D=32 on fp16 rows (s2 fused into pass 0)
    const int aggGrid = (N + 31) / 32;
    agg32_kernel<0><<<aggGrid, 256, 0, stream>>>(y, dinv, rowptr, csr, s1, s2, c1, c2, b3, z, N);
    agg32_kernel<1><<<aggGrid, 256, 0, stream>>>(z, dinv, rowptr, csr, s1, s2, c1, c2, b3, y, N);
    agg32_kernel<2><<<aggGrid, 256, 0, stream>>>(y, dinv, rowptr, csr, s1, s2, c1, c2, b3, out, N);
}

// Round 13
// 206.167 us; speedup vs baseline: 1.0477x; 1.0477x over previous
//
#include <hip/hip_runtime.h>
#include <hip/hip_fp16.h>
#include <math.h>

// GCN 3-layer, no inter-layer nonlinearity -> algebraic collapse:
//   out = sigmoid( A^3 (x @ Wc) + s2*c1 + s1*c2 + b3 )
//   Wc = W1@W2@W3, c1 = b1@W2@W3, c2 = b2@W3, s1 = A*1, s2 = A*s1
// CSR build: zero global atomics (two-level LDS bucket sort).
// CSR entry packed to 4B: u32 = (fp16_bits(nrm) << 17) | src (nrm>0 -> 15b).
// Aggregation: 3 passes at D=32 on fp16 rows. Each node's edge list is
// processed by TWO 8-thread groups on alternating 4-edge chunks (doubles
// memory-level parallelism at constant VGPR), combined via one LDS reduce.

#define EPB 4096   // edges per pass-1 block
#define MAXBKT 512 // >= ceil(N/256)

__device__ __forceinline__ float unpack_w(unsigned u) {
    return __half2float(__ushort_as_half((unsigned short)(u >> 17)));
}
__device__ __forceinline__ unsigned pack_sw(int src, float w) {
    unsigned wb = (unsigned)__half_as_ushort(__float2half_rn(w)) & 0x7FFFu;
    return (wb << 17) | (unsigned)src;
}

// ---------- 1a: per-block bucket histogram (LDS atomics only) ----------
__global__ __launch_bounds__(256) void hist1_kernel(const int* __restrict__ ei,
                                                    int* __restrict__ hist1,
                                                    int nbkt, int nblk1, int E) {
    __shared__ int lh[MAXBKT];
    int tid = threadIdx.x;
    for (int b = tid; b < nbkt; b += 256) lh[b] = 0;
    __syncthreads();
    int base = blockIdx.x * EPB;
    #pragma unroll
    for (int j = 0; j < EPB / 256; ++j) {
        int e = base + j * 256 + tid;
        if (e < E) atomicAdd(&lh[ei[E + e] >> 8], 1);
    }
    __syncthreads();
    for (int b = tid; b < nbkt; b += 256)
        hist1[(size_t)b * nblk1 + blockIdx.x] = lh[b];
}

// ---------- hierarchical exclusive scan ----------
__global__ void scan_block_kernel(const int* __restrict__ counts, int* __restrict__ outp,
                                  int* __restrict__ bsums, int n) {
    __shared__ int s[256];
    int tid = threadIdx.x;
    int i = blockIdx.x * 256 + tid;
    int v = (i < n) ? counts[i] : 0;
    s[tid] = v;
    __syncthreads();
    for (int off = 1; off < 256; off <<= 1) {
        int t = (tid >= off) ? s[tid - off] : 0;
        __syncthreads();
        s[tid] += t;
        __syncthreads();
    }
    if (i < n) outp[i] = s[tid] - v;
    if (tid == 255) bsums[blockIdx.x] = s[255];
}

__global__ void scan_bsums_kernel(int* __restrict__ bsums, int nb) {
    __shared__ int s[1024];
    int tid = threadIdx.x;
    int v = (tid < nb) ? bsums[tid] : 0;
    s[tid] = v;
    __syncthreads();
    for (int off = 1; off < 1024; off <<= 1) {
        int t = (tid >= off) ? s[tid - off] : 0;
        __syncthreads();
        s[tid] += t;
        __syncthreads();
    }
    if (tid < nb) bsums[tid] = s[tid] - v;
}

__global__ void scan_add_kernel(int* __restrict__ outp, const int* __restrict__ bsums,
                                int n, int E) {
    int i = blockIdx.x * 256 + threadIdx.x;
    if (i < n) outp[i] += bsums[i >> 8];
    if (i == n) outp[n] = E;   // sentinel
}

// ---------- 1c: scatter edges to bucket-ordered tmp (LDS cursors) ----------
__global__ __launch_bounds__(256) void bucket_scatter_kernel(const int* __restrict__ ei,
                                                             const float* __restrict__ ew,
                                                             const int* __restrict__ scan1,
                                                             int2* __restrict__ tmp,
                                                             int nbkt, int nblk1, int E) {
    __shared__ int cur[MAXBKT];
    int tid = threadIdx.x;
    for (int b = tid; b < nbkt; b += 256)
        cur[b] = scan1[(size_t)b * nblk1 + blockIdx.x];
    __syncthreads();
    int base = blockIdx.x * EPB;
    #pragma unroll
    for (int j = 0; j < EPB / 256; ++j) {
        int e = base + j * 256 + tid;
        if (e < E) {
            int s = ei[e];
            int d = ei[E + e];
            float w = ew[e];
            int pos = atomicAdd(&cur[d >> 8], 1);
            tmp[pos] = make_int2(s | ((d & 255) << 20), __float_as_int(w));
        }
    }
}

// ---------- 2: per-bucket build: rowptr, packed csr, dinv (all LDS-local) ----------
__global__ __launch_bounds__(256) void bucket_build_kernel(const int* __restrict__ scan1,
                                                           const int2* __restrict__ tmp,
                                                           int* __restrict__ rowptr,
                                                           unsigned* __restrict__ csr,
                                                           float* __restrict__ dinv,
                                                           int nblk1, int N, int E) {
    __shared__ int s[256];
    __shared__ int cur[256];
    __shared__ float wsum[256];
    int b = blockIdx.x;
    int tid = threadIdx.x;
    int beg = scan1[(size_t)b * nblk1];
    int end = scan1[(size_t)(b + 1) * nblk1];

    s[tid] = 0;
    wsum[tid] = 0.f;
    __syncthreads();
    for (int i = beg + tid; i < end; i += 256) {
        int2 r = tmp[i];
        int dl = r.x >> 20;
        atomicAdd(&s[dl], 1);
        atomicAdd(&wsum[dl], __int_as_float(r.y));   // fp32 weights -> exact deg
    }
    __syncthreads();
    int myc = s[tid];
    for (int off = 1; off < 256; off <<= 1) {
        int t = (tid >= off) ? s[tid - off] : 0;
        __syncthreads();
        s[tid] += t;
        __syncthreads();
    }
    int excl = s[tid] - myc;
    cur[tid] = excl;
    int node = b * 256 + tid;
    if (node <= N) rowptr[node] = beg + excl;
    if (node < N)  dinv[node] = rsqrtf(1.0f + wsum[tid]);
    __syncthreads();
    for (int i = beg + tid; i < end; i += 256) {
        int2 r = tmp[i];
        int dl = r.x >> 20;
        int pos = beg + atomicAdd(&cur[dl], 1);
        csr[pos] = pack_sw(r.x & 0xFFFFF, __int_as_float(r.y));
    }
}

// ---------- nrm finalize (in place, packed) + s1 = A*1 ----------
__global__ void nrm_s1_kernel(const float* __restrict__ dinv, const int* __restrict__ rowptr,
                              unsigned* __restrict__ csr, float* __restrict__ s1, int n) {
    int v = blockIdx.x * 256 + threadIdx.x;
    if (v >= n) return;
    float dv = dinv[v];
    float acc = dv * dv;
    int beg = rowptr[v], end = rowptr[v + 1];
    for (int i = beg; i < end; ++i) {
        unsigned u = csr[i];
        int src = u & 0x1FFFF;
        float nm = dv * unpack_w(u) * dinv[src];
        acc += nm;
        csr[i] = pack_sw(src, nm);
    }
    s1[v] = acc;
}

// ---------- compose1: U = [W1;b1] @ W2  (65 rows, K=128) ----------
__global__ __launch_bounds__(256) void compose1_kernel(const float* __restrict__ W1,
                                                       const float* __restrict__ b1,
                                                       const float* __restrict__ W2,
                                                       float* __restrict__ U) {
    __shared__ float s[256];
    int r = blockIdx.x;
    int tid = threadIdx.x;
    int c = tid & 63;
    int q = tid >> 6;
    const float* arow = (r < 64) ? &W1[r * 128] : b1;
    float acc = 0.f;
    #pragma unroll 8
    for (int k = q * 32; k < q * 32 + 32; ++k)
        acc += arow[k] * W2[k * 64 + c];
    s[tid] = acc;
    __syncthreads();
    if (q == 0)
        U[r * 64 + c] = s[c] + s[c + 64] + s[c + 128] + s[c + 192];
}

// ---------- compose2: U@W3 -> Wc,c1 ; b2@W3 -> c2 (K=64) ----------
__global__ __launch_bounds__(256) void compose2_kernel(const float* __restrict__ U,
                                                       const float* __restrict__ b2,
                                                       const float* __restrict__ W3,
                                                       float* __restrict__ Wc,
                                                       float* __restrict__ c1,
                                                       float* __restrict__ c2) {
    __shared__ float s[256];
    int r = blockIdx.x;
    int tid = threadIdx.x;
    int c = tid & 31;
    int o = tid >> 5;
    const float* arow = (r < 65) ? &U[r * 64] : b2;
    float acc = 0.f;
    #pragma unroll
    for (int k = o * 8; k < o * 8 + 8; ++k)
        acc += arow[k] * W3[k * 32 + c];
    s[tid] = acc;
    __syncthreads();
    if (o == 0) {
        float v = 0.f;
        #pragma unroll
        for (int j = 0; j < 8; ++j) v += s[c + j * 32];
        if (r < 64) Wc[r * 32 + c] = v;
        else if (r == 64) c1[c] = v;
        else c2[c] = v;
    }
}

// ---------- GEMM: T[n, 32] = X[n, 64] @ Wc[64, 32], output fp16 ----------
template <int K, int D>
__global__ __launch_bounds__(256) void gemm_kernel(const float* __restrict__ X,
                                                   const float* __restrict__ W,
                                                   __half* __restrict__ T, int n) {
    constexpr int NB = 64;
    __shared__ float sW[K * D];
    __shared__ float sX[NB * K];
    int tid = threadIdx.x;
    int base = blockIdx.x * NB;
    int nthis = n - base;
    if (nthis > NB) nthis = NB;

    for (int i = tid * 4; i < K * D; i += 256 * 4)
        *(float4*)&sW[i] = *(const float4*)&W[i];
    for (int i = tid * 4; i < nthis * K; i += 256 * 4)
        *(float4*)&sX[i] = *(const float4*)&X[(size_t)base * K + i];
    __syncthreads();

    constexpr int C4 = D / 4;
    constexpr int NG = 256 / C4;
    int c4 = tid % C4;
    int ng = tid / C4;
    for (int nl = ng; nl < nthis; nl += NG) {
        const float* xr = &sX[nl * K];
        float4 acc = {0.f, 0.f, 0.f, 0.f};
        #pragma unroll
        for (int k = 0; k < K; ++k) {
            float a = xr[k];
            float4 wv = *(const float4*)&sW[k * D + c4 * 4];
            acc.x += a * wv.x; acc.y += a * wv.y;
            acc.z += a * wv.z; acc.w += a * wv.w;
        }
        __half2 h0 = __floats2half2_rn(acc.x, acc.y);
        __half2 h1 = __floats2half2_rn(acc.z, acc.w);
        uint2 u = { *(unsigned*)&h0, *(unsigned*)&h1 };
        *(uint2*)&T[(size_t)(base + nl) * D + c4 * 4] = u;
    }
}

// ---------- agg32: 16 threads/node (2 groups x 8), 4 gathers in flight/group ----------
template <int PHASE>
__global__ __launch_bounds__(256) void agg32_kernel(const __half* __restrict__ T,
                                                    const float* __restrict__ dinv,
                                                    const int* __restrict__ rowptr,
                                                    const unsigned* __restrict__ csr,
                                                    const float* __restrict__ s1,
                                                    float* __restrict__ s2,
                                                    const float* __restrict__ c1,
                                                    const float* __restrict__ c2,
                                                    const float* __restrict__ b3,
                                                    void* __restrict__ outp, int n) {
    __shared__ float4 pacc[256];
    __shared__ float  psac[256];
    int tid = threadIdx.x;
    int c4 = tid & 7;                    // column quad 0..7 (32 cols)
    int h  = (tid >> 3) & 1;             // edge group 0/1
    int node = blockIdx.x * 16 + (tid >> 4);
    bool active = node < n;

    int beg = 0, end = 0;
    if (active) { beg = rowptr[node]; end = rowptr[node + 1]; }
    int len = end - beg;

    float4 acc = {0.f, 0.f, 0.f, 0.f};
    float sacc = 0.f;

    // group h processes 4-edge chunks h, h+2, h+4, ... (interleaved)
    for (int i = beg + 4 * h; i + 4 <= end; i += 8) {
        unsigned u0 = csr[i];
        unsigned u1 = csr[i + 1];
        unsigned u2 = csr[i + 2];
        unsigned u3 = csr[i + 3];
        int s0 = u0 & 0x1FFFF;
        int s1i = u1 & 0x1FFFF;
        int s2i = u2 & 0x1FFFF;
        int s3 = u3 & 0x1FFFF;
        uint2 g0 = *(const uint2*)&T[(size_t)s0 * 32 + c4 * 4];
        uint2 g1 = *(const uint2*)&T[(size_t)s1i * 32 + c4 * 4];
        uint2 g2 = *(const uint2*)&T[(size_t)s2i * 32 + c4 * 4];
        uint2 g3 = *(const uint2*)&T[(size_t)s3 * 32 + c4 * 4];
        float w0 = unpack_w(u0);
        float w1 = unpack_w(u1);
        float w2 = unpack_w(u2);
        float w3 = unpack_w(u3);
        float2 a0 = __half22float2(*(__half2*)&g0.x);
        float2 a1 = __half22float2(*(__half2*)&g0.y);
        float2 b0 = __half22float2(*(__half2*)&g1.x);
        float2 b1 = __half22float2(*(__half2*)&g1.y);
        float2 e0 = __half22float2(*(__half2*)&g2.x);
        float2 e1 = __half22float2(*(__half2*)&g2.y);
        float2 f0 = __half22float2(*(__half2*)&g3.x);
        float2 f1 = __half22float2(*(__half2*)&g3.y);
        acc.x += w0 * a0.x + w1 * b0.x + w2 * e0.x + w3 * f0.x;
        acc.y += w0 * a0.y + w1 * b0.y + w2 * e0.y + w3 * f0.y;
        acc.z += w0 * a1.x + w1 * b1.x + w2 * e1.x + w3 * f1.x;
        acc.w += w0 * a1.y + w1 * b1.y + w2 * e1.y + w3 * f1.y;
        if (PHASE == 0) sacc += w0 * s1[s0] + w1 * s1[s1i] + w2 * s1[s2i] + w3 * s1[s3];
    }
    // tail (< 4 edges) + self term: group 0 only
    if (h == 0) {
        for (int i = beg + (len & ~3); i < end; ++i) {
            unsigned u0 = csr[i];
            int s0 = u0 & 0x1FFFF;
            uint2 g0 = *(const uint2*)&T[(size_t)s0 * 32 + c4 * 4];
            float w0 = unpack_w(u0);
            float2 a0 = __half22float2(*(__half2*)&g0.x);
            float2 a1 = __half22float2(*(__half2*)&g0.y);
            acc.x += w0 * a0.x;
            acc.y += w0 * a0.y;
            acc.z += w0 * a1.x;
            acc.w += w0 * a1.y;
            if (PHASE == 0) sacc += w0 * s1[s0];
        }
        if (active) {
            float di = dinv[node];
            float ns = di * di;
            uint2 tu = *(const uint2*)&T[(size_t)node * 32 + c4 * 4];
            float2 t0 = __half22float2(*(__half2*)&tu.x);
            float2 t1 = __half22float2(*(__half2*)&tu.y);
            acc.x += t0.x * ns; acc.y += t0.y * ns;
            acc.z += t1.x * ns; acc.w += t1.y * ns;
            if (PHASE == 0) sacc += ns * s1[node];
        }
    }

    pacc[tid] = acc;
    if (PHASE == 0) psac[tid] = sacc;
    __syncthreads();

    if (h == 0 && active) {
        float4 o = pacc[tid + 8];
        acc.x += o.x; acc.y += o.y; acc.z += o.z; acc.w += o.w;
        if (PHASE == 0) {
            sacc += psac[tid + 8];
            if (c4 == 0) s2[node] = sacc;
        }
        if (PHASE == 2) {
            float a = s2[node], b = s1[node];
            float4 c1v = *(const float4*)&c1[c4 * 4];
            float4 c2v = *(const float4*)&c2[c4 * 4];
            float4 b3v = *(const float4*)&b3[c4 * 4];
            acc.x += a * c1v.x + b * c2v.x + b3v.x;
            acc.y += a * c1v.y + b * c2v.y + b3v.y;
            acc.z += a * c1v.z + b * c2v.z + b3v.z;
            acc.w += a * c1v.w + b * c2v.w + b3v.w;
            acc.x = 1.f / (1.f + __expf(-acc.x));
            acc.y = 1.f / (1.f + __expf(-acc.y));
            acc.z = 1.f / (1.f + __expf(-acc.z));
            acc.w = 1.f / (1.f + __expf(-acc.w));
            *(float4*)&((float*)outp)[(size_t)node * 32 + c4 * 4] = acc;
        } else {
            __half2 h0 = __floats2half2_rn(acc.x, acc.y);
            __half2 h1 = __floats2half2_rn(acc.z, acc.w);
            uint2 u = { *(unsigned*)&h0, *(unsigned*)&h1 };
            *(uint2*)&((__half*)outp)[(size_t)node * 32 + c4 * 4] = u;
        }
    }
}

extern "C" void kernel_launch(void* const* d_in, const int* in_sizes, int n_in,
                              void* d_out, int out_size, void* d_ws, size_t ws_size,
                              hipStream_t stream) {
    const float* x  = (const float*)d_in[0];
    const int*   ei = (const int*)d_in[1];      // [2, E]: row=ei[0:E], col=ei[E:2E]
    const float* ew = (const float*)d_in[2];
    const float* W1 = (const float*)d_in[3];
    const float* b1 = (const float*)d_in[4];
    const float* W2 = (const float*)d_in[5];
    const float* b2 = (const float*)d_in[6];
    const float* W3 = (const float*)d_in[7];
    const float* b3 = (const float*)d_in[8];
    float* out = (float*)d_out;

    const int N = in_sizes[0] / 64;
    const int E = in_sizes[2];

    const int nbkt  = (N + 255) >> 8;
    const int nblk1 = (E + EPB - 1) / EPB;
    const int nscan = nbkt * nblk1;

    auto a16 = [](size_t v) { return (v + 15) & ~(size_t)15; };
    char* p = (char*)d_ws;
    int*      hist1  = (int*)p;      p += a16((size_t)nscan * 4);
    int*      scan1  = (int*)p;      p += a16((size_t)(nscan + 1) * 4);
    int*      bsums  = (int*)p;      p += a16((size_t)1024 * 4);
    int2*     tmp    = (int2*)p;     p += a16((size_t)E * 8);
    int*      rowptr = (int*)p;      p += a16((size_t)(N + 1) * 4);
    unsigned* csr    = (unsigned*)p; p += a16((size_t)E * 4);   // packed {nrm15|src17}
    float*    dinv   = (float*)p;    p += a16((size_t)N * 4);
    float*    s1     = (float*)p;    p += a16((size_t)N * 4);
    float*    s2     = (float*)p;    p += a16((size_t)N * 4);
    float*    Uc     = (float*)p;    p += a16((size_t)65 * 64 * 4);
    float*    Wc     = (float*)p;    p += a16((size_t)64 * 32 * 4);
    float*    c1     = (float*)p;    p += a16((size_t)32 * 4);
    float*    c2     = (float*)p;    p += a16((size_t)32 * 4);
    __half*   y      = (__half*)p;   p += a16((size_t)N * 32 * 2);
    __half*   z      = (__half*)p;   p += a16((size_t)N * 32 * 2);

    const int nbN = (N + 255) / 256;
    const int scanBlocks = (nscan + 255) / 256;

    // CSR build: LDS bucket sort, zero global atomics
    hist1_kernel<<<nblk1, 256, 0, stream>>>(ei, hist1, nbkt, nblk1, E);
    scan_block_kernel<<<scanBlocks, 256, 0, stream>>>(hist1, scan1, bsums, nscan);
    scan_bsums_kernel<<<1, 1024, 0, stream>>>(bsums, scanBlocks);
    scan_add_kernel<<<(nscan + 1 + 255) / 256, 256, 0, stream>>>(scan1, bsums, nscan, E);
    bucket_scatter_kernel<<<nblk1, 256, 0, stream>>>(ei, ew, scan1, tmp, nbkt, nblk1, E);
    bucket_build_kernel<<<nbkt, 256, 0, stream>>>(scan1, tmp, rowptr, csr, dinv, nblk1, N, E);

    // Normalization from CSR
    nrm_s1_kernel<<<nbN, 256, 0, stream>>>(dinv, rowptr, csr, s1, N);

    // Collapsed weights (row-parallel) + dense transform (fp16 rows out)
    compose1_kernel<<<65, 256, 0, stream>>>(W1, b1, W2, Uc);
    compose2_kernel<<<66, 256, 0, stream>>>(Uc, b2, W3, Wc, c1, c2);
    gemm_kernel<64, 32><<<(N + 63) / 64, 256, 0, stream>>>(x, Wc, y, N);

    // Three sparse passes at D=32 on fp16 rows (s2 fused into pass 0)
    const int aggGrid = (N + 15) / 16;
    agg32_kernel<0><<<aggGrid, 256, 0, stream>>>(y, dinv, rowptr, csr, s1, s2, c1, c2, b3, z, N);
    agg32_kernel<1><<<aggGrid, 256, 0, stream>>>(z, dinv, rowptr, csr, s1, s2, c1, c2, b3, y, N);
    agg32_kernel<2><<<aggGrid, 256, 0, stream>>>(y, dinv, rowptr, csr, s1, s2, c1, c2, b3, out, N);
}

// Round 14
// 200.439 us; speedup vs baseline: 1.0776x; 1.0286x over previous
//
#include <hip/hip_runtime.h>
#include <hip/hip_fp16.h>
#include <math.h>

// GCN 3-layer, no inter-layer nonlinearity -> algebraic collapse:
//   out = sigmoid( A^3 (x @ Wc) + s2*c1 + s1*c2 + b3 )
//   Wc = W1@W2@W3, c1 = b1@W2@W3, c2 = b2@W3, s1 = A*1, s2 = A*s1
// CSR build: zero global atomics (two-level LDS bucket sort).
// CSR entry packed to 4B: u32 = (fp16_bits(nrm) << 17) | src.
//   - src: 17 bits (N=100K < 2^17)
//   - nrm > 0 -> fp16 sign bit = 0 -> 15 bits hold the full fp16 value
// Halves the edge-stream traffic in all three aggregation passes.
// Aggregation: 3 passes at D=32 on fp16 rows (64B = one line per gather),
// 4 gathers in flight; s2 fused into pass 0. All math fp32.
// FINAL CONFIG (best measured 200.4us): R12's 8-wide ILP (-occupancy) and
// R13's 16-thread/node TLP both measured null-to-negative -> the agg passes
// run at the random-64B-gather fabric ceiling (~2.2 TB/s effective).

#define EPB 4096   // edges per pass-1 block
#define MAXBKT 512 // >= ceil(N/256)

__device__ __forceinline__ float unpack_w(unsigned u) {
    return __half2float(__ushort_as_half((unsigned short)(u >> 17)));
}
__device__ __forceinline__ unsigned pack_sw(int src, float w) {
    unsigned wb = (unsigned)__half_as_ushort(__float2half_rn(w)) & 0x7FFFu;
    return (wb << 17) | (unsigned)src;
}

// ---------- 1a: per-block bucket histogram (LDS atomics only) ----------
__global__ __launch_bounds__(256) void hist1_kernel(const int* __restrict__ ei,
                                                    int* __restrict__ hist1,
                                                    int nbkt, int nblk1, int E) {
    __shared__ int lh[MAXBKT];
    int tid = threadIdx.x;
    for (int b = tid; b < nbkt; b += 256) lh[b] = 0;
    __syncthreads();
    int base = blockIdx.x * EPB;
    #pragma unroll
    for (int j = 0; j < EPB / 256; ++j) {
        int e = base + j * 256 + tid;
        if (e < E) atomicAdd(&lh[ei[E + e] >> 8], 1);
    }
    __syncthreads();
    for (int b = tid; b < nbkt; b += 256)
        hist1[(size_t)b * nblk1 + blockIdx.x] = lh[b];
}

// ---------- hierarchical exclusive scan ----------
__global__ void scan_block_kernel(const int* __restrict__ counts, int* __restrict__ outp,
                                  int* __restrict__ bsums, int n) {
    __shared__ int s[256];
    int tid = threadIdx.x;
    int i = blockIdx.x * 256 + tid;
    int v = (i < n) ? counts[i] : 0;
    s[tid] = v;
    __syncthreads();
    for (int off = 1; off < 256; off <<= 1) {
        int t = (tid >= off) ? s[tid - off] : 0;
        __syncthreads();
        s[tid] += t;
        __syncthreads();
    }
    if (i < n) outp[i] = s[tid] - v;
    if (tid == 255) bsums[blockIdx.x] = s[255];
}

__global__ void scan_bsums_kernel(int* __restrict__ bsums, int nb) {
    __shared__ int s[1024];
    int tid = threadIdx.x;
    int v = (tid < nb) ? bsums[tid] : 0;
    s[tid] = v;
    __syncthreads();
    for (int off = 1; off < 1024; off <<= 1) {
        int t = (tid >= off) ? s[tid - off] : 0;
        __syncthreads();
        s[tid] += t;
        __syncthreads();
    }
    if (tid < nb) bsums[tid] = s[tid] - v;
}

__global__ void scan_add_kernel(int* __restrict__ outp, const int* __restrict__ bsums,
                                int n, int E) {
    int i = blockIdx.x * 256 + threadIdx.x;
    if (i < n) outp[i] += bsums[i >> 8];
    if (i == n) outp[n] = E;   // sentinel
}

// ---------- 1c: scatter edges to bucket-ordered tmp (LDS cursors) ----------
__global__ __launch_bounds__(256) void bucket_scatter_kernel(const int* __restrict__ ei,
                                                             const float* __restrict__ ew,
                                                             const int* __restrict__ scan1,
                                                             int2* __restrict__ tmp,
                                                             int nbkt, int nblk1, int E) {
    __shared__ int cur[MAXBKT];
    int tid = threadIdx.x;
    for (int b = tid; b < nbkt; b += 256)
        cur[b] = scan1[(size_t)b * nblk1 + blockIdx.x];
    __syncthreads();
    int base = blockIdx.x * EPB;
    #pragma unroll
    for (int j = 0; j < EPB / 256; ++j) {
        int e = base + j * 256 + tid;
        if (e < E) {
            int s = ei[e];
            int d = ei[E + e];
            float w = ew[e];
            int pos = atomicAdd(&cur[d >> 8], 1);
            tmp[pos] = make_int2(s | ((d & 255) << 20), __float_as_int(w));
        }
    }
}

// ---------- 2: per-bucket build: rowptr, packed csr, dinv (all LDS-local) ----------
__global__ __launch_bounds__(256) void bucket_build_kernel(const int* __restrict__ scan1,
                                                           const int2* __restrict__ tmp,
                                                           int* __restrict__ rowptr,
                                                           unsigned* __restrict__ csr,
                                                           float* __restrict__ dinv,
                                                           int nblk1, int N, int E) {
    __shared__ int s[256];
    __shared__ int cur[256];
    __shared__ float wsum[256];
    int b = blockIdx.x;
    int tid = threadIdx.x;
    int beg = scan1[(size_t)b * nblk1];
    int end = scan1[(size_t)(b + 1) * nblk1];

    s[tid] = 0;
    wsum[tid] = 0.f;
    __syncthreads();
    for (int i = beg + tid; i < end; i += 256) {
        int2 r = tmp[i];
        int dl = r.x >> 20;
        atomicAdd(&s[dl], 1);
        atomicAdd(&wsum[dl], __int_as_float(r.y));   // fp32 weights -> exact deg
    }
    __syncthreads();
    int myc = s[tid];
    for (int off = 1; off < 256; off <<= 1) {
        int t = (tid >= off) ? s[tid - off] : 0;
        __syncthreads();
        s[tid] += t;
        __syncthreads();
    }
    int excl = s[tid] - myc;
    cur[tid] = excl;
    int node = b * 256 + tid;
    if (node <= N) rowptr[node] = beg + excl;
    if (node < N)  dinv[node] = rsqrtf(1.0f + wsum[tid]);
    __syncthreads();
    for (int i = beg + tid; i < end; i += 256) {
        int2 r = tmp[i];
        int dl = r.x >> 20;
        int pos = beg + atomicAdd(&cur[dl], 1);
        csr[pos] = pack_sw(r.x & 0xFFFFF, __int_as_float(r.y));
    }
}

// ---------- nrm finalize (in place, packed) + s1 = A*1 ----------
__global__ void nrm_s1_kernel(const float* __restrict__ dinv, const int* __restrict__ rowptr,
                              unsigned* __restrict__ csr, float* __restrict__ s1, int n) {
    int v = blockIdx.x * 256 + threadIdx.x;
    if (v >= n) return;
    float dv = dinv[v];
    float acc = dv * dv;
    int beg = rowptr[v], end = rowptr[v + 1];
    for (int i = beg; i < end; ++i) {
        unsigned u = csr[i];
        int src = u & 0x1FFFF;
        float nm = dv * unpack_w(u) * dinv[src];
        acc += nm;
        csr[i] = pack_sw(src, nm);
    }
    s1[v] = acc;
}

// ---------- compose1: U = [W1;b1] @ W2  (65 rows, K=128) ----------
__global__ __launch_bounds__(256) void compose1_kernel(const float* __restrict__ W1,
                                                       const float* __restrict__ b1,
                                                       const float* __restrict__ W2,
                                                       float* __restrict__ U) {
    __shared__ float s[256];
    int r = blockIdx.x;
    int tid = threadIdx.x;
    int c = tid & 63;
    int q = tid >> 6;
    const float* arow = (r < 64) ? &W1[r * 128] : b1;
    float acc = 0.f;
    #pragma unroll 8
    for (int k = q * 32; k < q * 32 + 32; ++k)
        acc += arow[k] * W2[k * 64 + c];
    s[tid] = acc;
    __syncthreads();
    if (q == 0)
        U[r * 64 + c] = s[c] + s[c + 64] + s[c + 128] + s[c + 192];
}

// ---------- compose2: U@W3 -> Wc,c1 ; b2@W3 -> c2 (K=64) ----------
__global__ __launch_bounds__(256) void compose2_kernel(const float* __restrict__ U,
                                                       const float* __restrict__ b2,
                                                       const float* __restrict__ W3,
                                                       float* __restrict__ Wc,
                                                       float* __restrict__ c1,
                                                       float* __restrict__ c2) {
    __shared__ float s[256];
    int r = blockIdx.x;
    int tid = threadIdx.x;
    int c = tid & 31;
    int o = tid >> 5;
    const float* arow = (r < 65) ? &U[r * 64] : b2;
    float acc = 0.f;
    #pragma unroll
    for (int k = o * 8; k < o * 8 + 8; ++k)
        acc += arow[k] * W3[k * 32 + c];
    s[tid] = acc;
    __syncthreads();
    if (o == 0) {
        float v = 0.f;
        #pragma unroll
        for (int j = 0; j < 8; ++j) v += s[c + j * 32];
        if (r < 64) Wc[r * 32 + c] = v;
        else if (r == 64) c1[c] = v;
        else c2[c] = v;
    }
}

// ---------- GEMM: T[n, 32] = X[n, 64] @ Wc[64, 32], output fp16 ----------
template <int K, int D>
__global__ __launch_bounds__(256) void gemm_kernel(const float* __restrict__ X,
                                                   const float* __restrict__ W,
                                                   __half* __restrict__ T, int n) {
    constexpr int NB = 64;
    __shared__ float sW[K * D];
    __shared__ float sX[NB * K];
    int tid = threadIdx.x;
    int base = blockIdx.x * NB;
    int nthis = n - base;
    if (nthis > NB) nthis = NB;

    for (int i = tid * 4; i < K * D; i += 256 * 4)
        *(float4*)&sW[i] = *(const float4*)&W[i];
    for (int i = tid * 4; i < nthis * K; i += 256 * 4)
        *(float4*)&sX[i] = *(const float4*)&X[(size_t)base * K + i];
    __syncthreads();

    constexpr int C4 = D / 4;
    constexpr int NG = 256 / C4;
    int c4 = tid % C4;
    int ng = tid / C4;
    for (int nl = ng; nl < nthis; nl += NG) {
        const float* xr = &sX[nl * K];
        float4 acc = {0.f, 0.f, 0.f, 0.f};
        #pragma unroll
        for (int k = 0; k < K; ++k) {
            float a = xr[k];
            float4 wv = *(const float4*)&sW[k * D + c4 * 4];
            acc.x += a * wv.x; acc.y += a * wv.y;
            acc.z += a * wv.z; acc.w += a * wv.w;
        }
        __half2 h0 = __floats2half2_rn(acc.x, acc.y);
        __half2 h1 = __floats2half2_rn(acc.z, acc.w);
        uint2 u = { *(unsigned*)&h0, *(unsigned*)&h1 };
        *(uint2*)&T[(size_t)(base + nl) * D + c4 * 4] = u;
    }
}

// ---------- agg32 on fp16 rows, packed 4B csr, 4 gathers in flight ----------
template <int PHASE>
__global__ __launch_bounds__(256) void agg32_kernel(const __half* __restrict__ T,
                                                    const float* __restrict__ dinv,
                                                    const int* __restrict__ rowptr,
                                                    const unsigned* __restrict__ csr,
                                                    const float* __restrict__ s1,
                                                    float* __restrict__ s2,
                                                    const float* __restrict__ c1,
                                                    const float* __restrict__ c2,
                                                    const float* __restrict__ b3,
                                                    void* __restrict__ outp, int n) {
    int c4 = threadIdx.x & 7;                       // 8 lanes x 4 halves = 32 cols
    int node = blockIdx.x * 32 + (threadIdx.x >> 3);
    if (node >= n) return;

    float di = dinv[node];
    float ns = di * di;
    uint2 tu = *(const uint2*)&T[(size_t)node * 32 + c4 * 4];
    float2 t0 = __half22float2(*(__half2*)&tu.x);
    float2 t1 = __half22float2(*(__half2*)&tu.y);
    float4 acc = { t0.x * ns, t0.y * ns, t1.x * ns, t1.y * ns };
    float sacc = (PHASE == 0) ? ns * s1[node] : 0.f;

    int beg = rowptr[node];
    int end = rowptr[node + 1];
    int i = beg;
    for (; i + 4 <= end; i += 4) {
        unsigned u0 = csr[i];
        unsigned u1 = csr[i + 1];
        unsigned u2 = csr[i + 2];
        unsigned u3 = csr[i + 3];
        int s0 = u0 & 0x1FFFF;
        int s1i = u1 & 0x1FFFF;
        int s2i = u2 & 0x1FFFF;
        int s3 = u3 & 0x1FFFF;
        uint2 g0 = *(const uint2*)&T[(size_t)s0 * 32 + c4 * 4];
        uint2 g1 = *(const uint2*)&T[(size_t)s1i * 32 + c4 * 4];
        uint2 g2 = *(const uint2*)&T[(size_t)s2i * 32 + c4 * 4];
        uint2 g3 = *(const uint2*)&T[(size_t)s3 * 32 + c4 * 4];
        float w0 = unpack_w(u0);
        float w1 = unpack_w(u1);
        float w2 = unpack_w(u2);
        float w3 = unpack_w(u3);
        float2 a0 = __half22float2(*(__half2*)&g0.x);
        float2 a1 = __half22float2(*(__half2*)&g0.y);
        float2 b0 = __half22float2(*(__half2*)&g1.x);
        float2 b1 = __half22float2(*(__half2*)&g1.y);
        float2 e0 = __half22float2(*(__half2*)&g2.x);
        float2 e1 = __half22float2(*(__half2*)&g2.y);
        float2 f0 = __half22float2(*(__half2*)&g3.x);
        float2 f1 = __half22float2(*(__half2*)&g3.y);
        acc.x += w0 * a0.x + w1 * b0.x + w2 * e0.x + w3 * f0.x;
        acc.y += w0 * a0.y + w1 * b0.y + w2 * e0.y + w3 * f0.y;
        acc.z += w0 * a1.x + w1 * b1.x + w2 * e1.x + w3 * f1.x;
        acc.w += w0 * a1.y + w1 * b1.y + w2 * e1.y + w3 * f1.y;
        if (PHASE == 0) sacc += w0 * s1[s0] + w1 * s1[s1i] + w2 * s1[s2i] + w3 * s1[s3];
    }
    for (; i < end; ++i) {
        unsigned u0 = csr[i];
        int s0 = u0 & 0x1FFFF;
        uint2 g0 = *(const uint2*)&T[(size_t)s0 * 32 + c4 * 4];
        float w0 = unpack_w(u0);
        float2 a0 = __half22float2(*(__half2*)&g0.x);
        float2 a1 = __half22float2(*(__half2*)&g0.y);
        acc.x += w0 * a0.x;
        acc.y += w0 * a0.y;
        acc.z += w0 * a1.x;
        acc.w += w0 * a1.y;
        if (PHASE == 0) sacc += w0 * s1[s0];
    }

    if (PHASE == 0 && c4 == 0) s2[node] = sacc;

    if (PHASE == 2) {
        float a = s2[node], b = s1[node];
        float4 c1v = *(const float4*)&c1[c4 * 4];
        float4 c2v = *(const float4*)&c2[c4 * 4];
        float4 b3v = *(const float4*)&b3[c4 * 4];
        acc.x += a * c1v.x + b * c2v.x + b3v.x;
        acc.y += a * c1v.y + b * c2v.y + b3v.y;
        acc.z += a * c1v.z + b * c2v.z + b3v.z;
        acc.w += a * c1v.w + b * c2v.w + b3v.w;
        acc.x = 1.f / (1.f + __expf(-acc.x));
        acc.y = 1.f / (1.f + __expf(-acc.y));
        acc.z = 1.f / (1.f + __expf(-acc.z));
        acc.w = 1.f / (1.f + __expf(-acc.w));
        *(float4*)&((float*)outp)[(size_t)node * 32 + c4 * 4] = acc;
    } else {
        __half2 h0 = __floats2half2_rn(acc.x, acc.y);
        __half2 h1 = __floats2half2_rn(acc.z, acc.w);
        uint2 u = { *(unsigned*)&h0, *(unsigned*)&h1 };
        *(uint2*)&((__half*)outp)[(size_t)node * 32 + c4 * 4] = u;
    }
}

extern "C" void kernel_launch(void* const* d_in, const int* in_sizes, int n_in,
                              void* d_out, int out_size, void* d_ws, size_t ws_size,
                              hipStream_t stream) {
    const float* x  = (const float*)d_in[0];
    const int*   ei = (const int*)d_in[1];      // [2, E]: row=ei[0:E], col=ei[E:2E]
    const float* ew = (const float*)d_in[2];
    const float* W1 = (const float*)d_in[3];
    const float* b1 = (const float*)d_in[4];
    const float* W2 = (const float*)d_in[5];
    const float* b2 = (const float*)d_in[6];
    const float* W3 = (const float*)d_in[7];
    const float* b3 = (const float*)d_in[8];
    float* out = (float*)d_out;

    const int N = in_sizes[0] / 64;
    const int E = in_sizes[2];

    const int nbkt  = (N + 255) >> 8;
    const int nblk1 = (E + EPB - 1) / EPB;
    const int nscan = nbkt * nblk1;

    auto a16 = [](size_t v) { return (v + 15) & ~(size_t)15; };
    char* p = (char*)d_ws;
    int*      hist1  = (int*)p;      p += a16((size_t)nscan * 4);
    int*      scan1  = (int*)p;      p += a16((size_t)(nscan + 1) * 4);
    int*      bsums  = (int*)p;      p += a16((size_t)1024 * 4);
    int2*     tmp    = (int2*)p;     p += a16((size_t)E * 8);
    int*      rowptr = (int*)p;      p += a16((size_t)(N + 1) * 4);
    unsigned* csr    = (unsigned*)p; p += a16((size_t)E * 4);   // packed {nrm15|src17}
    float*    dinv   = (float*)p;    p += a16((size_t)N * 4);
    float*    s1     = (float*)p;    p += a16((size_t)N * 4);
    float*    s2     = (float*)p;    p += a16((size_t)N * 4);
    float*    Uc     = (float*)p;    p += a16((size_t)65 * 64 * 4);
    float*    Wc     = (float*)p;    p += a16((size_t)64 * 32 * 4);
    float*    c1     = (float*)p;    p += a16((size_t)32 * 4);
    float*    c2     = (float*)p;    p += a16((size_t)32 * 4);
    __half*   y      = (__half*)p;   p += a16((size_t)N * 32 * 2);
    __half*   z      = (__half*)p;   p += a16((size_t)N * 32 * 2);

    const int nbN = (N + 255) / 256;
    const int scanBlocks = (nscan + 255) / 256;

    // CSR build: LDS bucket sort, zero global atomics
    hist1_kernel<<<nblk1, 256, 0, stream>>>(ei, hist1, nbkt, nblk1, E);
    scan_block_kernel<<<scanBlocks, 256, 0, stream>>>(hist1, scan1, bsums, nscan);
    scan_bsums_kernel<<<1, 1024, 0, stream>>>(bsums, scanBlocks);
    scan_add_kernel<<<(nscan + 1 + 255) / 256, 256, 0, stream>>>(scan1, bsums, nscan, E);
    bucket_scatter_kernel<<<nblk1, 256, 0, stream>>>(ei, ew, scan1, tmp, nbkt, nblk1, E);
    bucket_build_kernel<<<nbkt, 256, 0, stream>>>(scan1, tmp, rowptr, csr, dinv, nblk1, N, E);

    // Normalization from CSR
    nrm_s1_kernel<<<nbN, 256, 0, stream>>>(dinv, rowptr, csr, s1, N);

    // Collapsed weights (row-parallel) + dense transform (fp16 rows out)
    compose1_kernel<<<65, 256, 0, stream>>>(W1, b1, W2, Uc);
    compose2_kernel<<<66, 256, 0, stream>>>(Uc, b2, W3, Wc, c1, c2);
    gemm_kernel<64, 32><<<(N + 63) / 64, 256, 0, stream>>>(x, Wc, y, N);

    // Three sparse passes at D=32 on fp16 rows (s2 fused into pass 0)
    const int aggGrid = (N + 31) / 32;
    agg32_kernel<0><<<aggGrid, 256, 0, stream>>>(y, dinv, rowptr, csr, s1, s2, c1, c2, b3, z, N);
    agg32_kernel<1><<<aggGrid, 256, 0, stream>>>(z, dinv, rowptr, csr, s1, s2, c1, c2, b3, y, N);
    agg32_kernel<2><<<aggGrid, 256, 0, stream>>>(y, dinv, rowptr, csr, s1, s2, c1, c2, b3, out, N);
}